// Round 10
// baseline (138.501 us; speedup 1.0000x reference)
//
#include <hip/hip_runtime.h>
#include <stdint.h>

#define Bd 8
#define Rr 5
#define Nn 1024
#define Dd 512
#define KK (Rr*Dd) /* 2560 */

typedef __attribute__((ext_vector_type(8))) short bf16x8;
typedef __attribute__((ext_vector_type(4))) float f32x4;
typedef unsigned short u16;
typedef unsigned int u32;

__device__ __forceinline__ u16 f2bf(float x){
  union { float f; unsigned u; } v; v.f = x;
  unsigned r = v.u + 0x7FFFu + ((v.u >> 16) & 1u);
  return (u16)(r >> 16);
}

// ---------------- K1: prep ----------------
// g < 2048:          hTp[b][ut][dt][dr][uu] = bf16 h[b][ut*32+uu][dt*16+dr]
// g in [2048,3328):  Wt2p[kt][et][er][kk] = bf16 W[rmap(k)][et*16+er][dmap(k)]
//                    k = kt*32+kk; k<2048: r=1+(k>>9), d=k&511; else r=0, d=k-2048
__global__ __launch_bounds__(256) void k_prep(
    const float* __restrict__ h, const float* __restrict__ W,
    u16* __restrict__ hTp, u16* __restrict__ Wt2p){
  __shared__ float t32[32][65];
  const int tid = threadIdx.x;
  const int g = blockIdx.x;
  if (g < 2048){
    const int ut  = g & 31;
    const int dtg = (g >> 5) & 7;
    const int b   = g >> 8;
    const float* hb = h + ((size_t)b*Nn + (size_t)ut*32)*Dd + dtg*64;
    #pragma unroll
    for (int j=0;j<8;j++){
      int e = j*256 + tid;
      int ul = e >> 6, dl = e & 63;
      t32[ul][dl] = hb[(size_t)ul*Dd + dl];
    }
    __syncthreads();
    u16* ob = hTp + (size_t)b*Dd*Nn;
    #pragma unroll
    for (int j=0;j<8;j++){
      int e = j*256 + tid;
      int dtl = e >> 9;
      int rem = e & 511;
      int dr = rem >> 5, uu = rem & 31;
      int dt = dtg*4 + dtl;
      ob[((size_t)ut*32 + dt)*512 + rem] = f2bf(t32[uu][dtl*16 + dr]);
    }
  } else {
    int q = (g - 2048)*1024 + tid*4;       // over 512*2560, 4 u16 along kk
    int kk = q & 31;
    int er = (q >> 5) & 15;
    int et = (q >> 9) & 31;
    int kt = q >> 14;
    int k = kt*32 + kk;
    int e = et*16 + er;
    int r, d;
    if (k < 2048){ r = 1 + (k >> 9); d = k & 511; }
    else         { r = 0;            d = k - 2048; }
    f32x4 w = *(const f32x4*)(W + (((size_t)r*Dd + e)*Dd + d));
    u16 o[4] = { f2bf(w.x), f2bf(w.y), f2bf(w.z), f2bf(w.w) };
    *(uint2*)(Wt2p + q) = *(uint2*)o;       // dest flat index == q
  }
}

// ---------------- K2: fully fused GCN layer ----------------
// Per block (b, 32 v-rows): phase1 = r-fused adj GEMM (R9 pipeline, 2-deep adj
// prefetch); phase2 = per-relation second GEMM vs prepacked Wt2p, acc2[e][v];
// phase3 = relu + residual + LayerNorm -> out. No msg/agg materialization.
__global__ __launch_bounds__(512,2) void k_fused(
    const float* __restrict__ adj, const u16* __restrict__ hTp,
    const u16* __restrict__ Wt2p, const float* __restrict__ h,
    const float* __restrict__ gamma, const float* __restrict__ beta,
    float* __restrict__ out){
  __shared__ __align__(16) u16 sA[2][4][32*64];   // 32KB adj double-buffer
  __shared__ __align__(16) u16 sBt[32*512];       // 32KB phase-2 B tile [v][d]
  __shared__ float sT[16*516];                    // 33KB transpose/LN buffer
  __shared__ float sDeg[4][32];

  const int tid  = threadIdx.x;
  const int lane = tid & 63;
  const int wave = tid >> 6;
  const int b  = blockIdx.x & 7;     // b -> XCD (L2 locality)
  const int vt = blockIdx.x >> 3;
  const int v0 = vt * 32;
  const int t0 = blockIdx.x & 15;
  const float* adjb = adj + (((size_t)b*Rr + 1)*Nn + v0)*Nn;  // r=1 base
  const u16* hTpb = hTp + (size_t)b*Dd*Nn;

  const int srow = tid >> 4;         // 0..31
  const int sc   = tid & 15;
  const size_t aoff = (size_t)srow*Nn + sc*4;
  const int wslot = sc ^ ((srow & 7) << 1);

  float deg[4] = {0.f,0.f,0.f,0.f};
  f32x4 aregA[4], aregB[4];
  f32x4 acc[4][2][4];
  #pragma unroll
  for (int ri=0;ri<4;ri++)
    #pragma unroll
    for (int m=0;m<2;m++)
      #pragma unroll
      for (int n=0;n<4;n++) acc[ri][m][n] = (f32x4){0.f,0.f,0.f,0.f};

  const int rlo = lane & 15, ch = lane >> 4;
  const int boff = rlo*32 + ch*8;

  #define TT(x) (((x) + t0) & 15)

  #define AISSUE(REG, T) do {                                                 \
    _Pragma("unroll")                                                         \
    for (int ri=0;ri<4;ri++)                                                  \
      REG[ri] = *(const f32x4*)(adjb + (size_t)ri*Nn*Nn + (size_t)(T)*64 + aoff); \
  } while(0)

  #define PACK(REG, BUFI) do {                                                \
    _Pragma("unroll")                                                         \
    for (int ri=0;ri<4;ri++){                                                 \
      f32x4 p = REG[ri];                                                      \
      deg[ri] += p.x+p.y+p.z+p.w;                                             \
      uint2 pk;  /* adj in {0,1}: truncation exact */                         \
      pk.x = (__float_as_uint(p.x)>>16) | (__float_as_uint(p.y) & 0xFFFF0000u);\
      pk.y = (__float_as_uint(p.z)>>16) | (__float_as_uint(p.w) & 0xFFFF0000u);\
      *(uint2*)((char*)sA[BUFI][ri] + srow*128 + wslot*8) = pk;               \
    }                                                                         \
  } while(0)

  #define LOADB(T) do {                                                      \
    _Pragma("unroll")                                                         \
    for (int kk=0;kk<2;kk++){                                                 \
      const u16* bp = hTpb + ((((size_t)((T)*2+kk))*32 + (wave<<2))<<9) + boff;\
      _Pragma("unroll")                                                       \
      for (int n=0;n<4;n++)                                                   \
        bfr[kk][n] = *(const bf16x8*)(bp + ((size_t)n<<9));                   \
    }                                                                         \
  } while(0)

  #define MSTEP(BUFI) do {                                                    \
    const char* abase = (const char*)sA[BUFI];                                \
    _Pragma("unroll")                                                         \
    for (int kk=0;kk<2;kk++){                                                 \
      _Pragma("unroll")                                                       \
      for (int ri=0;ri<4;ri++){                                               \
        bf16x8 af[2];                                                         \
        _Pragma("unroll")                                                     \
        for (int m=0;m<2;m++){                                                \
          const int row = m*16 + rlo;                                         \
          af[m] = *(const bf16x8*)(abase + ri*4096 + row*128                  \
                    + (((kk*8 + ch*2) ^ ((row&7)<<1))<<3));                   \
        }                                                                     \
        _Pragma("unroll")                                                     \
        for (int m=0;m<2;m++)                                                 \
          _Pragma("unroll")                                                   \
          for (int n=0;n<4;n++)                                               \
            acc[ri][m][n] = __builtin_amdgcn_mfma_f32_16x16x32_bf16(          \
                af[m], bfr[kk][n], acc[ri][m][n], 0, 0, 0);                   \
      }                                                                       \
    }                                                                         \
  } while(0)

  #define FENCE() __builtin_amdgcn_sched_barrier(0)
  #define STEP_BARRIER() do {                                                 \
    asm volatile("s_waitcnt lgkmcnt(0)" ::: "memory");                        \
    FENCE();                                                                  \
    __builtin_amdgcn_s_barrier();                                             \
    FENCE();                                                                  \
  } while(0)

  bf16x8 bfr[2][4];

  // ---- phase 1 prologue ----
  AISSUE(aregA, TT(0));
  PACK(aregA, 0);
  __syncthreads();
  AISSUE(aregA, TT(1));
  FENCE();
  AISSUE(aregB, TT(2));
  FENCE();
  LOADB(TT(0));
  FENCE();

  for (int t = 0; t < 14; t += 2){
    // even t: consume aregA = adj(t+1)
    PACK(aregA, 1);
    FENCE();
    if (t < 13) AISSUE(aregA, TT(t+3));
    FENCE();
    MSTEP(0);
    FENCE();
    LOADB(TT(t+1));
    STEP_BARRIER();
    // odd t+1: consume aregB = adj(t+2)
    PACK(aregB, 0);
    FENCE();
    if (t+1 < 13) AISSUE(aregB, TT(t+4));
    FENCE();
    MSTEP(1);
    FENCE();
    LOADB(TT(t+2));
    STEP_BARRIER();
  }
  { // t = 14: aregA = adj(15)
    PACK(aregA, 1);
    FENCE();
    MSTEP(0);
    FENCE();
    LOADB(TT(15));
    STEP_BARRIER();
  }
  MSTEP(1);  // t = 15
  #undef TT
  #undef AISSUE
  #undef PACK
  #undef LOADB
  #undef MSTEP

  // deg reduce over the 16 threads sharing srow
  #pragma unroll
  for (int ri=0;ri<4;ri++){
    float d = deg[ri];
    d += __shfl_xor(d, 1); d += __shfl_xor(d, 2);
    d += __shfl_xor(d, 4); d += __shfl_xor(d, 8);
    if (sc == 0) sDeg[ri][srow] = d;
  }
  __syncthreads();

  // ---- phase 2: acc2[e][v] = sum_k Wt2[e][k] * msg[v][k] over K=2560 ----
  f32x4 acc2[4][2];
  #pragma unroll
  for (int m=0;m<4;m++)
    #pragma unroll
    for (int n=0;n<2;n++) acc2[m][n] = (f32x4){0.f,0.f,0.f,0.f};

  #pragma unroll
  for (int p=0; p<5; ++p){
    // build B-tile sBt[v][d] bf16, 16B-slot swizzled by (v&7)
    if (p < 4){
      #pragma unroll
      for (int m=0;m<2;m++)
        #pragma unroll
        for (int reg=0;reg<4;reg++){
          const int v = m*16 + ch*4 + reg;
          const float inv = 1.0f / fmaxf(sDeg[p][v], 1.0f);
          #pragma unroll
          for (int n=0;n<4;n++){
            const int d = (wave<<6) + n*16 + rlo;
            sBt[v*512 + ((((d>>3) ^ (v&7))<<3) | (d&7))] =
                f2bf(acc[p][m][n][reg] * inv);
          }
        }
    } else {
      const int v = tid >> 4;
      const float* hp = h + ((size_t)b*Nn + v0 + v)*Dd + (tid&15)*32;
      #pragma unroll
      for (int j=0;j<4;j++){
        f32x4 a = *(const f32x4*)(hp + j*8);
        f32x4 c = *(const f32x4*)(hp + j*8 + 4);
        bf16x8 pk;
        pk[0]=(short)f2bf(a.x); pk[1]=(short)f2bf(a.y);
        pk[2]=(short)f2bf(a.z); pk[3]=(short)f2bf(a.w);
        pk[4]=(short)f2bf(c.x); pk[5]=(short)f2bf(c.y);
        pk[6]=(short)f2bf(c.z); pk[7]=(short)f2bf(c.w);
        const int d0 = (tid&15)*32 + j*8;
        *(bf16x8*)&sBt[v*512 + (((d0>>3) ^ (v&7))<<3)] = pk;
      }
    }
    __syncthreads();
    #pragma unroll
    for (int s=0; s<16; ++s){
      const int kt = p*16 + s;
      bf16x8 wfr[4], btf[2];
      #pragma unroll
      for (int m=0;m<4;m++){
        const int et = (wave<<2) + m;
        wfr[m] = *(const bf16x8*)(Wt2p + (((size_t)kt*32 + et)<<9) + boff);
      }
      #pragma unroll
      for (int n=0;n<2;n++){
        const int v = n*16 + rlo;
        btf[n] = *(const bf16x8*)&sBt[v*512 + ((((s*4 + ch) ^ (v&7)))<<3)];
      }
      #pragma unroll
      for (int m=0;m<4;m++)
        #pragma unroll
        for (int n=0;n<2;n++)
          acc2[m][n] = __builtin_amdgcn_mfma_f32_16x16x32_bf16(
              wfr[m], btf[n], acc2[m][n], 0, 0, 0);
    }
    __syncthreads();
  }

  // ---- phase 3: relu + residual + LayerNorm -> out ----
  // acc2[m][n]: e = wave*64 + m*16 + ch*4 + reg, v = n*16 + rlo
  #pragma unroll
  for (int hh=0; hh<2; ++hh){
    #pragma unroll
    for (int m=0;m<4;m++)
      #pragma unroll
      for (int reg=0;reg<4;reg++){
        const int col = (wave<<6) + m*16 + ch*4 + reg;
        const int colw = col ^ (((col>>5)&7)<<2);
        sT[rlo*516 + colw] = fmaxf(acc2[m][hh][reg], 0.f);
      }
    __syncthreads();
    {
      const int row = wave*2 + (lane>>5);     // 0..15
      const int elane = lane & 31;
      const int grow = v0 + hh*16 + row;
      const float* hp = h + ((size_t)b*Nn + grow)*Dd + elane*16;
      float x[16];
      float sum = 0.f, sq = 0.f;
      #pragma unroll
      for (int j=0;j<4;j++){
        const int col = elane*16 + j*4;
        const int colw = col ^ (((col>>5)&7)<<2);
        f32x4 sv = *(const f32x4*)&sT[row*516 + colw];
        f32x4 hv = *(const f32x4*)(hp + j*4);
        #pragma unroll
        for (int k=0;k<4;k++){
          float val = sv[k] + hv[k];
          x[j*4+k] = val; sum += val; sq += val*val;
        }
      }
      #pragma unroll
      for (int off=16; off; off>>=1){
        sum += __shfl_xor(sum, off);
        sq  += __shfl_xor(sq,  off);
      }
      const float mu  = sum * (1.f/(float)Dd);
      const float var = sq * (1.f/(float)Dd) - mu*mu;
      const float rstd = rsqrtf(var + 1e-5f);
      float* op = out + ((size_t)b*Nn + grow)*Dd + elane*16;
      #pragma unroll
      for (int j=0;j<4;j++){
        f32x4 g  = *(const f32x4*)(gamma + elane*16 + j*4);
        f32x4 be = *(const f32x4*)(beta  + elane*16 + j*4);
        f32x4 ov;
        #pragma unroll
        for (int k=0;k<4;k++)
          ov[k] = (x[j*4+k] - mu) * rstd * g[k] + be[k];
        *(f32x4*)(op + j*4) = ov;
      }
    }
    __syncthreads();
  }
  #undef FENCE
  #undef STEP_BARRIER
}

extern "C" void kernel_launch(void* const* d_in, const int* in_sizes, int n_in,
                              void* d_out, int out_size, void* d_ws, size_t ws_size,
                              hipStream_t stream){
  const float* h     = (const float*)d_in[0];
  const float* adj   = (const float*)d_in[1];
  const float* W     = (const float*)d_in[2];
  const float* gamma = (const float*)d_in[3];
  const float* beta  = (const float*)d_in[4];
  float* out = (float*)d_out;
  char* ws = (char*)d_ws;

  u16*  hTp  = (u16*)(ws);                //  8,388,608  (Bd*Dd*Nn*2)
  u16*  Wt2p = (u16*)(ws + 8388608);      //  2,621,440  (Dd*KK*2)

  k_prep <<<dim3(3328), dim3(256), 0, stream>>>(h, W, hTp, Wt2p);
  k_fused<<<dim3(Bd*32), dim3(512), 0, stream>>>(adj, hTp, Wt2p, h, gamma, beta, out);
}

// Round 11
// 105.739 us; speedup vs baseline: 1.3098x; 1.3098x over previous
//
#include <hip/hip_runtime.h>
#include <stdint.h>

#define Bd 8
#define Rr 5
#define Nn 1024
#define Dd 512
#define KK (Rr*Dd) /* 2560 */

typedef __attribute__((ext_vector_type(8))) short bf16x8;
typedef __attribute__((ext_vector_type(4))) float f32x4;
typedef unsigned short u16;
typedef unsigned int u32;

__device__ __forceinline__ u16 f2bf(float x){
  union { float f; unsigned u; } v; v.f = x;
  unsigned r = v.u + 0x7FFFu + ((v.u >> 16) & 1u);
  return (u16)(r >> 16);
}

// ---------------- K1: prep ----------------
// g < 2048:          hTp[b][ut][dt][dr][uu] = bf16 h[b][ut*32+uu][dt*16+dr]
// g in [2048,3328):  Wt2p[kt][et][er][kk] = bf16 W[rmap(k)][et*16+er][dmap(k)]
//                    k = kt*32+kk; k<2048: r=1+(k>>9), d=k&511; else r=0, d=k-2048
__global__ __launch_bounds__(256) void k_prep(
    const float* __restrict__ h, const float* __restrict__ W,
    u16* __restrict__ hTp, u16* __restrict__ Wt2p){
  __shared__ float t32[32][65];
  const int tid = threadIdx.x;
  const int g = blockIdx.x;
  if (g < 2048){
    const int ut  = g & 31;
    const int dtg = (g >> 5) & 7;
    const int b   = g >> 8;
    const float* hb = h + ((size_t)b*Nn + (size_t)ut*32)*Dd + dtg*64;
    #pragma unroll
    for (int j=0;j<8;j++){
      int e = j*256 + tid;
      int ul = e >> 6, dl = e & 63;
      t32[ul][dl] = hb[(size_t)ul*Dd + dl];
    }
    __syncthreads();
    u16* ob = hTp + (size_t)b*Dd*Nn;
    #pragma unroll
    for (int j=0;j<8;j++){
      int e = j*256 + tid;
      int dtl = e >> 9;
      int rem = e & 511;
      int dr = rem >> 5, uu = rem & 31;
      int dt = dtg*4 + dtl;
      ob[((size_t)ut*32 + dt)*512 + rem] = f2bf(t32[uu][dtl*16 + dr]);
    }
  } else {
    int q = (g - 2048)*1024 + tid*4;       // over 512*2560, 4 u16 along kk
    int kk = q & 31;
    int er = (q >> 5) & 15;
    int et = (q >> 9) & 31;
    int kt = q >> 14;
    int k = kt*32 + kk;
    int e = et*16 + er;
    int r, d;
    if (k < 2048){ r = 1 + (k >> 9); d = k & 511; }
    else         { r = 0;            d = k - 2048; }
    f32x4 w = *(const f32x4*)(W + (((size_t)r*Dd + e)*Dd + d));
    u16 o[4] = { f2bf(w.x), f2bf(w.y), f2bf(w.z), f2bf(w.w) };
    *(uint2*)(Wt2p + q) = *(uint2*)o;       // dest flat index == q
  }
}

// ---------------- K2: fully fused GCN layer ----------------
// Per block (b, 32 v-rows): phase1 = r-fused adj GEMM (R9 single-areg pipeline);
// phase2 = per-relation second GEMM vs prepacked Wt2p, acc2[e][v];
// phase3 = relu + residual + LayerNorm -> out. No msg/agg materialization.
// Register budget (512-thr block => <=256 unified): acc 128 AGPR + bfr 32 +
// areg 16 + addressing ~ 240 peak. Spill-free is the point of this revision.
__global__ __launch_bounds__(512,2) void k_fused(
    const float* __restrict__ adj, const u16* __restrict__ hTp,
    const u16* __restrict__ Wt2p, const float* __restrict__ h,
    const float* __restrict__ gamma, const float* __restrict__ beta,
    float* __restrict__ out){
  __shared__ __align__(16) u16 sA[2][4][32*64];   // 32KB adj double-buffer
  __shared__ __align__(16) u16 sBt[32*512];       // 32KB phase-2 B tile [v][d]
  __shared__ float sT[16*516];                    // 33KB transpose/LN buffer
  __shared__ float sDeg[4][32];

  const int tid  = threadIdx.x;
  const int lane = tid & 63;
  const int wave = tid >> 6;
  const int b  = blockIdx.x & 7;     // b -> XCD (L2 locality)
  const int vt = blockIdx.x >> 3;
  const int v0 = vt * 32;
  const int t0 = blockIdx.x & 15;
  const float* adjb = adj + (((size_t)b*Rr + 1)*Nn + v0)*Nn;  // r=1 base
  const u16* hTpb = hTp + (size_t)b*Dd*Nn;

  const int srow = tid >> 4;         // 0..31
  const int sc   = tid & 15;
  const size_t aoff = (size_t)srow*Nn + sc*4;
  const int wslot = sc ^ ((srow & 7) << 1);

  float deg[4] = {0.f,0.f,0.f,0.f};
  f32x4 areg[4];
  f32x4 acc[4][2][4];
  #pragma unroll
  for (int ri=0;ri<4;ri++)
    #pragma unroll
    for (int m=0;m<2;m++)
      #pragma unroll
      for (int n=0;n<4;n++) acc[ri][m][n] = (f32x4){0.f,0.f,0.f,0.f};

  const int rlo = lane & 15, ch = lane >> 4;
  const int boff = rlo*32 + ch*8;

  #define TT(x) (((x) + t0) & 15)

  #define AISSUE(T) do {                                                      \
    _Pragma("unroll")                                                         \
    for (int ri=0;ri<4;ri++)                                                  \
      areg[ri] = *(const f32x4*)(adjb + (size_t)ri*Nn*Nn + (size_t)(T)*64 + aoff); \
  } while(0)

  #define PACK(BUFI) do {                                                     \
    _Pragma("unroll")                                                         \
    for (int ri=0;ri<4;ri++){                                                 \
      f32x4 p = areg[ri];                                                     \
      deg[ri] += p.x+p.y+p.z+p.w;                                             \
      uint2 pk;  /* adj in {0,1}: truncation exact */                         \
      pk.x = (__float_as_uint(p.x)>>16) | (__float_as_uint(p.y) & 0xFFFF0000u);\
      pk.y = (__float_as_uint(p.z)>>16) | (__float_as_uint(p.w) & 0xFFFF0000u);\
      *(uint2*)((char*)sA[BUFI][ri] + srow*128 + wslot*8) = pk;               \
    }                                                                         \
  } while(0)

  #define LOADB(T) do {                                                      \
    _Pragma("unroll")                                                         \
    for (int kk=0;kk<2;kk++){                                                 \
      const u16* bp = hTpb + ((((size_t)((T)*2+kk))*32 + (wave<<2))<<9) + boff;\
      _Pragma("unroll")                                                       \
      for (int n=0;n<4;n++)                                                   \
        bfr[kk][n] = *(const bf16x8*)(bp + ((size_t)n<<9));                   \
    }                                                                         \
  } while(0)

  #define MSTEP(BUFI) do {                                                    \
    const char* abase = (const char*)sA[BUFI];                                \
    _Pragma("unroll")                                                         \
    for (int kk=0;kk<2;kk++){                                                 \
      _Pragma("unroll")                                                       \
      for (int ri=0;ri<4;ri++){                                               \
        bf16x8 af[2];                                                         \
        _Pragma("unroll")                                                     \
        for (int m=0;m<2;m++){                                                \
          const int row = m*16 + rlo;                                         \
          af[m] = *(const bf16x8*)(abase + ri*4096 + row*128                  \
                    + (((kk*8 + ch*2) ^ ((row&7)<<1))<<3));                   \
        }                                                                     \
        _Pragma("unroll")                                                     \
        for (int m=0;m<2;m++)                                                 \
          _Pragma("unroll")                                                   \
          for (int n=0;n<4;n++)                                               \
            acc[ri][m][n] = __builtin_amdgcn_mfma_f32_16x16x32_bf16(          \
                af[m], bfr[kk][n], acc[ri][m][n], 0, 0, 0);                   \
      }                                                                       \
    }                                                                         \
  } while(0)

  #define FENCE() __builtin_amdgcn_sched_barrier(0)
  #define STEP_BARRIER() do {                                                 \
    asm volatile("s_waitcnt lgkmcnt(0)" ::: "memory");                        \
    FENCE();                                                                  \
    __builtin_amdgcn_s_barrier();                                             \
    FENCE();                                                                  \
  } while(0)

  bf16x8 bfr[2][4];

  // ---- phase 1 prologue (R9 single-areg pipeline) ----
  AISSUE(TT(0));
  PACK(0);
  __syncthreads();
  LOADB(TT(0));
  FENCE();
  AISSUE(TT(1));
  FENCE();

  for (int t = 0; t < 15; ++t){
    PACK((t+1)&1);             // consumes adj(t+1); vmcnt wait leaves B in flight
    FENCE();
    if (t < 14) AISSUE(TT(t+2));  // adj(t+2): ~1 full step in flight
    FENCE();
    MSTEP(t&1);                // bfr loaded last step: no exposed B wait
    FENCE();
    LOADB(TT(t+1));            // B(t+1) crosses the barrier in registers
    STEP_BARRIER();
  }
  MSTEP(1);                    // t = 15
  #undef TT
  #undef AISSUE
  #undef PACK
  #undef LOADB
  #undef MSTEP

  // deg reduce over the 16 threads sharing srow
  #pragma unroll
  for (int ri=0;ri<4;ri++){
    float d = deg[ri];
    d += __shfl_xor(d, 1); d += __shfl_xor(d, 2);
    d += __shfl_xor(d, 4); d += __shfl_xor(d, 8);
    if (sc == 0) sDeg[ri][srow] = d;
  }
  __syncthreads();

  // ---- phase 2: acc2[e][v] = sum_k Wt2[e][k] * msg[v][k] over K=2560 ----
  f32x4 acc2[4][2];
  #pragma unroll
  for (int m=0;m<4;m++)
    #pragma unroll
    for (int n=0;n<2;n++) acc2[m][n] = (f32x4){0.f,0.f,0.f,0.f};

  #pragma unroll
  for (int p=0; p<5; ++p){
    // build B-tile sBt[v][d] bf16, 16B-slot swizzled by (v&7)
    if (p < 4){
      #pragma unroll
      for (int m=0;m<2;m++)
        #pragma unroll
        for (int reg=0;reg<4;reg++){
          const int v = m*16 + ch*4 + reg;
          const float inv = 1.0f / fmaxf(sDeg[p][v], 1.0f);
          #pragma unroll
          for (int n=0;n<4;n++){
            const int d = (wave<<6) + n*16 + rlo;
            sBt[v*512 + ((((d>>3) ^ (v&7))<<3) | (d&7))] =
                f2bf(acc[p][m][n][reg] * inv);
          }
        }
    } else {
      const int v = tid >> 4;
      const float* hp = h + ((size_t)b*Nn + v0 + v)*Dd + (tid&15)*32;
      #pragma unroll
      for (int j=0;j<4;j++){
        f32x4 a = *(const f32x4*)(hp + j*8);
        f32x4 c = *(const f32x4*)(hp + j*8 + 4);
        bf16x8 pk;
        pk[0]=(short)f2bf(a.x); pk[1]=(short)f2bf(a.y);
        pk[2]=(short)f2bf(a.z); pk[3]=(short)f2bf(a.w);
        pk[4]=(short)f2bf(c.x); pk[5]=(short)f2bf(c.y);
        pk[6]=(short)f2bf(c.z); pk[7]=(short)f2bf(c.w);
        const int d0 = (tid&15)*32 + j*8;
        *(bf16x8*)&sBt[v*512 + (((d0>>3) ^ (v&7))<<3)] = pk;
      }
    }
    __syncthreads();
    #pragma unroll
    for (int s=0; s<16; ++s){
      const int kt = p*16 + s;
      bf16x8 wfr[4], btf[2];
      #pragma unroll
      for (int m=0;m<4;m++){
        const int et = (wave<<2) + m;
        wfr[m] = *(const bf16x8*)(Wt2p + (((size_t)kt*32 + et)<<9) + boff);
      }
      #pragma unroll
      for (int n=0;n<2;n++){
        const int v = n*16 + rlo;
        btf[n] = *(const bf16x8*)&sBt[v*512 + ((((s*4 + ch) ^ (v&7)))<<3)];
      }
      #pragma unroll
      for (int m=0;m<4;m++)
        #pragma unroll
        for (int n=0;n<2;n++)
          acc2[m][n] = __builtin_amdgcn_mfma_f32_16x16x32_bf16(
              wfr[m], btf[n], acc2[m][n], 0, 0, 0);
    }
    __syncthreads();
  }

  // ---- phase 3: relu + residual + LayerNorm -> out ----
  // acc2[m][n]: e = wave*64 + m*16 + ch*4 + reg, v = n*16 + rlo
  #pragma unroll
  for (int hh=0; hh<2; ++hh){
    #pragma unroll
    for (int m=0;m<4;m++)
      #pragma unroll
      for (int reg=0;reg<4;reg++){
        const int col = (wave<<6) + m*16 + ch*4 + reg;
        const int colw = col ^ (((col>>5)&7)<<2);
        sT[rlo*516 + colw] = fmaxf(acc2[m][hh][reg], 0.f);
      }
    __syncthreads();
    {
      const int row = wave*2 + (lane>>5);     // 0..15
      const int elane = lane & 31;
      const int grow = v0 + hh*16 + row;
      const float* hp = h + ((size_t)b*Nn + grow)*Dd + elane*16;
      float x[16];
      float sum = 0.f, sq = 0.f;
      #pragma unroll
      for (int j=0;j<4;j++){
        const int col = elane*16 + j*4;
        const int colw = col ^ (((col>>5)&7)<<2);
        f32x4 sv = *(const f32x4*)&sT[row*516 + colw];
        f32x4 hv = *(const f32x4*)(hp + j*4);
        #pragma unroll
        for (int k=0;k<4;k++){
          float val = sv[k] + hv[k];
          x[j*4+k] = val; sum += val; sq += val*val;
        }
      }
      #pragma unroll
      for (int off=16; off; off>>=1){
        sum += __shfl_xor(sum, off);
        sq  += __shfl_xor(sq,  off);
      }
      const float mu  = sum * (1.f/(float)Dd);
      const float var = sq * (1.f/(float)Dd) - mu*mu;
      const float rstd = rsqrtf(var + 1e-5f);
      float* op = out + ((size_t)b*Nn + grow)*Dd + elane*16;
      #pragma unroll
      for (int j=0;j<4;j++){
        f32x4 g  = *(const f32x4*)(gamma + elane*16 + j*4);
        f32x4 be = *(const f32x4*)(beta  + elane*16 + j*4);
        f32x4 ov;
        #pragma unroll
        for (int k=0;k<4;k++)
          ov[k] = (x[j*4+k] - mu) * rstd * g[k] + be[k];
        *(f32x4*)(op + j*4) = ov;
      }
    }
    __syncthreads();
  }
  #undef FENCE
  #undef STEP_BARRIER
}

extern "C" void kernel_launch(void* const* d_in, const int* in_sizes, int n_in,
                              void* d_out, int out_size, void* d_ws, size_t ws_size,
                              hipStream_t stream){
  const float* h     = (const float*)d_in[0];
  const float* adj   = (const float*)d_in[1];
  const float* W     = (const float*)d_in[2];
  const float* gamma = (const float*)d_in[3];
  const float* beta  = (const float*)d_in[4];
  float* out = (float*)d_out;
  char* ws = (char*)d_ws;

  u16*  hTp  = (u16*)(ws);                //  8,388,608  (Bd*Dd*Nn*2)
  u16*  Wt2p = (u16*)(ws + 8388608);      //  2,621,440  (Dd*KK*2)

  k_prep <<<dim3(3328), dim3(256), 0, stream>>>(h, W, hTp, Wt2p);
  k_fused<<<dim3(Bd*32), dim3(512), 0, stream>>>(adj, hTp, Wt2p, h, gamma, beta, out);
}